// Round 4
// baseline (203.326 us; speedup 1.0000x reference)
//
#include <hip/hip_runtime.h>
#include <hip/hip_cooperative_groups.h>
#include <stdint.h>

// Bitwise reproducibility vs the numpy reference: forbid a*b+c fusion so every
// mul/add rounds exactly like the ref (keep-decision booleans must not flip).
#pragma clang fp contract(off)

namespace cg = cooperative_groups;
typedef unsigned long long u64;
typedef unsigned int u32;

namespace {
constexpr int BB = 4;
constexpr int NN = 4096;
constexpr int CC = 64;
constexpr int BN = BB * NN;
constexpr float TARGET = 560.0f;
constexpr float MIN_BOX = 5.0f;
constexpr float IOU_THR = 0.2f;
constexpr float CONF_THR = 0.001f;
constexpr float BOX_CONF_THR = 0.01f;
constexpr float MAX_WH = 4096.0f;
constexpr int MAXK = 2048;   // per-(batch,class) hard cap; data has ~64 +/- 8 per class
}

__device__ __forceinline__ void zero_row(float* __restrict__ out, int p) {
    float2* o2 = (float2*)(out + (size_t)p * 6);   // p*24B is 8B-aligned
    float2 z; z.x = 0.0f; z.y = 0.0f;
    o2[0] = z; o2[1] = z; o2[2] = z;
}

// IoU(i,j) > thr with the ref's exact op order (offset boxes, precomputed areas,
// inter/(ai+aj-inter+1e-9) with IEEE division).
__device__ __forceinline__ bool iou_gt(float4 bi, float ai, float4 bj, float aj) {
    float ltx = fmaxf(bi.x, bj.x);
    float lty = fmaxf(bi.y, bj.y);
    float rbx = fminf(bi.z, bj.z);
    float rby = fminf(bi.w, bj.w);
    float ww = fmaxf(rbx - ltx, 0.0f);
    float hh = fmaxf(rby - lty, 0.0f);
    float inter = ww * hh;
    float iou = inter / (ai + aj - inter + 1e-9f);
    return iou > IOU_THR;
}

// One cooperative kernel, 256 blocks x 256 threads (1 block/CU co-resident).
// P1 score/key -> sync -> P2 rank-by-count -> sync -> P3 scatter -> sync -> P4 NMS+emit.
__global__ __launch_bounds__(256) void mega(const float* __restrict__ boxes,
                                            const float* __restrict__ box_scores,
                                            const float* __restrict__ cls_preds,
                                            float* __restrict__ out,
                                            float4* __restrict__ boxes_c,
                                            float* __restrict__ conf,
                                            int* __restrict__ clsval,
                                            u64* __restrict__ key64,
                                            int* __restrict__ rank,
                                            float4* __restrict__ sobox,
                                            float4* __restrict__ sdet,
                                            int* __restrict__ sclsv) {
    __shared__ float4 lbox[MAXK];   // 32 KB (fallback path; fast path uses [0..127])
    __shared__ int lpos[MAXK];      //  8 KB
    __shared__ float larea[128];
    const int bid = blockIdx.x;
    const int tid = threadIdx.x;

    // ================= Phase 1: clip, conf=max_c(cls*score), argmax, valid, key =====
    {
        int r = (bid << 6) + (tid >> 2);   // 64 rows/block, 4 lanes/row
        int sub = tid & 3;
        float bs = box_scores[r];
        const float4* cp = (const float4*)(cls_preds + ((size_t)r << 6) + (sub << 4));
        float best = -1.0f;   // products >= 0, so first element always beats init
        int bestc = sub << 4;
#pragma unroll
        for (int q = 0; q < 4; ++q) {
            float4 v = cp[q];
            float p0 = v.x * bs, p1 = v.y * bs, p2 = v.z * bs, p3 = v.w * bs;
            int cb = (sub << 4) + (q << 2);
            // strict > preserves numpy first-occurrence argmax within a lane
            if (p0 > best) { best = p0; bestc = cb + 0; }
            if (p1 > best) { best = p1; bestc = cb + 1; }
            if (p2 > best) { best = p2; bestc = cb + 2; }
            if (p3 > best) { best = p3; bestc = cb + 3; }
        }
        // quad merge; exact-tie -> smaller class index == first occurrence
#pragma unroll
        for (int d2 = 1; d2 < 4; d2 <<= 1) {
            float ob = __shfl_xor(best, d2);
            int oc = __shfl_xor(bestc, d2);
            if (ob > best || (ob == best && oc < bestc)) { best = ob; bestc = oc; }
        }
        if (sub == 0) {
            float4 bx = ((const float4*)boxes)[r];
            float x1 = fminf(fmaxf(bx.x, 0.0f), TARGET);
            float y1 = fminf(fmaxf(bx.y, 0.0f), TARGET);
            float x2 = fminf(fmaxf(bx.z, 0.0f), TARGET);
            float y2 = fminf(fmaxf(bx.w, 0.0f), TARGET);
            float w = x2 - x1, h = y2 - y1;
            bool valid = (bs > BOX_CONF_THR) && (w > MIN_BOX) && (h > MIN_BOX) && (best > CONF_THR);
            float sk = valid ? best : -1.0f;
            // monotonic float->uint map; unique 44-bit key: ties (all invalid at -1.0)
            // rank smaller original index first => stable descending sort.
            unsigned fb = __float_as_uint(sk);
            unsigned mm = (fb & 0x80000000u) ? ~fb : (fb | 0x80000000u);
            int i = r & (NN - 1);
            key64[r] = ((u64)mm << 12) | (u64)(NN - 1 - i);
            float4 bc; bc.x = x1; bc.y = y1; bc.z = x2; bc.w = y2;
            boxes_c[r] = bc;
            conf[r] = best;
            clsval[r] = bestc | (valid ? 0x10000 : 0);
            rank[r] = 0;   // phase 2 accumulates with atomics
        }
    }
    cg::this_grid().sync();

    // ================= Phase 2: rank_i = #{j in batch: key_j > key_i} ================
    {
        int q = bid & 63;
        int b = bid >> 6;
        int kseg = q & 3;           // which 1024-key chunk this block scans
        int eseg = q >> 2;          // which 256 elements this block owns
        const u64* kb = key64 + ((size_t)b << 12);
        int i = (eseg << 8) + tid;
        u64 my = kb[i];
        const u64* kp = kb + (kseg << 10);   // wave-uniform indices -> scalar loads
        int r = 0;
#pragma unroll 16
        for (int t2 = 0; t2 < 1024; ++t2) r += (int)(kp[t2] > my);
        atomicAdd(&rank[(b << 12) + i], r);
    }
    cg::this_grid().sync();

    // ================= Phase 3: scatter into sorted order (dst = rank) ===============
    if (tid < 64) {
        int e = (bid << 6) + tid;
        int b = bid >> 6;
        int dst = (b << 12) + rank[e];
        float4 bc = boxes_c[e];
        int cv = clsval[e];
        int c = cv & 0xFF;
        int valid = (cv >> 16) & 1;
        float off = (float)c * MAX_WH;   // exact (c*2^12); the + is the ref's one rounding
        float4 ob; ob.x = bc.x + off; ob.y = bc.y + off; ob.z = bc.z + off; ob.w = bc.w + off;
        sobox[dst] = ob;
        sdet[(size_t)dst * 2] = bc;
        float4 d1; d1.x = conf[e]; d1.y = (float)c; d1.z = 0.0f; d1.w = 0.0f;
        sdet[(size_t)dst * 2 + 1] = d1;
        sclsv[dst] = c | (valid << 8);
    }
    cg::this_grid().sync();

    // ================= Phase 4: per-(batch,class) greedy NMS + emit (wave0 only) =====
    // Cross-class IoU is exactly 0 (offset >= 4096 > extent), so global greedy NMS ==
    // independent per-class greedy in sorted order. This block owns every sorted
    // position with argmax class == myc: invalid -> zero row, suppressed -> zero row,
    // kept -> det row. Full coverage of d_out (poisoned each call).
    if (tid >= 64) return;
    const int lane = tid;
    const int b = bid >> 6;
    const int myc = bid & 63;
    const int base0 = b << 12;

    // --- compaction: lane owns 64 consecutive positions -> u64 masks, ONE shfl scan ---
    u64 mval = 0, minv = 0;
    {
        const int4* cvp = (const int4*)(sclsv + base0 + (lane << 6));
#pragma unroll
        for (int q = 0; q < 16; ++q) {
            int4 cv = cvp[q];   // 16 independent loads, one latency
            int bit = q << 2;
            if ((cv.x & 0xFF) == myc) { if ((cv.x >> 8) & 1) mval |= 1ull << (bit + 0); else minv |= 1ull << (bit + 0); }
            if ((cv.y & 0xFF) == myc) { if ((cv.y >> 8) & 1) mval |= 1ull << (bit + 1); else minv |= 1ull << (bit + 1); }
            if ((cv.z & 0xFF) == myc) { if ((cv.z >> 8) & 1) mval |= 1ull << (bit + 2); else minv |= 1ull << (bit + 2); }
            if ((cv.w & 0xFF) == myc) { if ((cv.w >> 8) & 1) mval |= 1ull << (bit + 3); else minv |= 1ull << (bit + 3); }
        }
    }
    int cnt = (int)__popcll(mval);
    int incl = cnt;
#pragma unroll
    for (int d2 = 1; d2 < 64; d2 <<= 1) {
        int t2 = __shfl_up(incl, d2);
        if (lane >= d2) incl += t2;
    }
    int kk = __shfl(incl, 63);
    // invalid-but-matching rows -> zeros
    {
        u64 t = minv;
        while (t) {
            int bb2 = (int)__builtin_ctzll(t); t &= t - 1;
            zero_row(out, base0 + (lane << 6) + bb2);
        }
    }
    // write lpos in ascending sorted-position order
    {
        int d = incl - cnt;
        u64 t = mval;
        while (t) {
            int bb2 = (int)__builtin_ctzll(t); t &= t - 1;
            int p = (lane << 6) + bb2;
            if (d < MAXK) lpos[d] = p; else zero_row(out, base0 + p);
            d++;
        }
    }
    if (kk > MAXK) kk = MAXK;
    if (kk == 0) return;

    if (kk <= 128) {
        // ---------- fast path: k x k IoU bit-matrix in registers, register-only scan --
        const int j0 = lane, j1 = 64 + lane;
        bool in0 = j0 < kk, in1 = j1 < kk;
        float4 box0 = {0, 0, 0, 0}, box1 = {0, 0, 0, 0};
        float a0 = 0.0f, a1 = 0.0f;
        if (in0) {
            box0 = sobox[base0 + lpos[j0]];
            a0 = (box0.z - box0.x) * (box0.w - box0.y);   // ref: area on offset boxes
            lbox[j0] = box0; larea[j0] = a0;
        }
        if (in1) {
            box1 = sobox[base0 + lpos[j1]];
            a1 = (box1.z - box1.x) * (box1.w - box1.y);
            lbox[j1] = box1; larea[j1] = a1;
        }
        u64 r00 = 0, r10 = 0, r11 = 0;   // column bit-rows: bit i = iou(i, j) > thr
        if (kk <= 64) {
            for (int i = 0; i < kk; ++i) {     // independent iterations -> pipelined
                float4 bi = lbox[i];
                float ai = larea[i];
                bool s0 = in0 && (j0 > i) && iou_gt(bi, ai, box0, a0);
                r00 |= ((u64)s0) << i;
            }
        } else {
            for (int i = 0; i < kk; ++i) {
                float4 bi = lbox[i];
                float ai = larea[i];
                bool s0 = in0 && (j0 > i) && iou_gt(bi, ai, box0, a0);
                bool s1 = in1 && (j1 > i) && iou_gt(bi, ai, box1, a1);
                if (i < 64) { r00 |= ((u64)s0) << i; r10 |= ((u64)s1) << i; }
                else        { r11 |= ((u64)s1) << (i - 64); }
            }
        }
        // greedy scan: ~15 register cycles per step
        u32 sup0 = 0, sup1 = 0;
        int kc = kk < 64 ? kk : 64;
        for (int i = 0; i < kc; ++i) {
            u64 f = __ballot(sup0 != 0);
            u32 km = ((f >> i) & 1ull) ? 0u : ~0u;   // keep_i mask
            sup0 |= km & (u32)((r00 >> i) & 1ull);
            sup1 |= km & (u32)((r10 >> i) & 1ull);
        }
        for (int i = 64; i < kk; ++i) {
            u64 f = __ballot(sup1 != 0);
            u32 km = ((f >> (i - 64)) & 1ull) ? 0u : ~0u;
            sup1 |= km & (u32)((r11 >> (i - 64)) & 1ull);
        }
        // emit
        if (in0) {
            int p = base0 + lpos[j0];
            if (!sup0) {
                const float4* dr = (const float4*)((const float*)sdet + (size_t)p * 8);
                float4 d0 = dr[0]; float4 d1 = dr[1];
                float2* o2 = (float2*)(out + (size_t)p * 6);
                float2 aa; aa.x = d0.x; aa.y = d0.y;
                float2 cc; cc.x = d0.z; cc.y = d0.w;
                float2 ee; ee.x = d1.x; ee.y = d1.y;
                o2[0] = aa; o2[1] = cc; o2[2] = ee;
            } else zero_row(out, p);
        }
        if (in1) {
            int p = base0 + lpos[j1];
            if (!sup1) {
                const float4* dr = (const float4*)((const float*)sdet + (size_t)p * 8);
                float4 d0 = dr[0]; float4 d1 = dr[1];
                float2* o2 = (float2*)(out + (size_t)p * 6);
                float2 aa; aa.x = d0.x; aa.y = d0.y;
                float2 cc; cc.x = d0.z; cc.y = d0.w;
                float2 ee; ee.x = d1.x; ee.y = d1.y;
                o2[0] = aa; o2[1] = cc; o2[2] = ee;
            } else zero_row(out, p);
        }
    } else {
        // ---------- general fallback (never taken on bench data; correctness net) ----
        for (int m = lane; m < kk; m += 64) lbox[m] = sobox[base0 + lpos[m]];
        u64 supw = 0;   // lane w owns suppression bits [64w, 64w+64)
        for (int i = 0; i < kk; ++i) {
            u64 wd = __shfl(supw, i >> 6);
            if (((wd >> (i & 63)) & 1ull) == 0ull) {
                float4 bi = lbox[i];
                float ai = (bi.z - bi.x) * (bi.w - bi.y);
                for (int jb = (i + 1) & ~63; jb < kk; jb += 64) {
                    int j = jb + lane;
                    bool s = false;
                    if (j > i && j < kk) {
                        float4 bj = lbox[j];
                        float aj = (bj.z - bj.x) * (bj.w - bj.y);
                        s = iou_gt(bi, ai, bj, aj);
                    }
                    u64 m2 = __ballot(s);
                    if (lane == (jb >> 6)) supw |= m2;
                }
            }
        }
        for (int t2 = 0; t2 * 64 < kk; ++t2) {
            int m = t2 * 64 + lane;
            u64 wd = __shfl(supw, t2);
            if (m < kk) {
                int p = base0 + lpos[m];
                if (((wd >> lane) & 1ull) == 0ull) {
                    const float4* dr = (const float4*)((const float*)sdet + (size_t)p * 8);
                    float4 d0 = dr[0]; float4 d1 = dr[1];
                    float2* o2 = (float2*)(out + (size_t)p * 6);
                    float2 aa; aa.x = d0.x; aa.y = d0.y;
                    float2 cc; cc.x = d0.z; cc.y = d0.w;
                    float2 ee; ee.x = d1.x; ee.y = d1.y;
                    o2[0] = aa; o2[1] = cc; o2[2] = ee;
                } else zero_row(out, p);
            }
        }
    }
}

extern "C" void kernel_launch(void* const* d_in, const int* in_sizes, int n_in,
                              void* d_out, int out_size, void* d_ws, size_t ws_size,
                              hipStream_t stream) {
    const float* boxes      = (const float*)d_in[0];   // [B,N,4]
    const float* box_scores = (const float*)d_in[1];   // [B,N]
    const float* cls_preds  = (const float*)d_in[2];   // [B,N,C]
    float* out = (float*)d_out;

    char* ws = (char*)d_ws;
    size_t off = 0;
    float4* boxes_c = (float4*)(ws + off); off += (size_t)BN * 16;      // 256 KB
    float4* sobox   = (float4*)(ws + off); off += (size_t)BN * 16;      // 256 KB
    float4* sdet    = (float4*)(ws + off); off += (size_t)BN * 32;      // 512 KB
    u64*    key64   = (u64*)(ws + off);    off += (size_t)BN * 8;       // 128 KB
    float*  conf    = (float*)(ws + off);  off += (size_t)BN * 4;       //  64 KB
    int*    clsval  = (int*)(ws + off);    off += (size_t)BN * 4;       //  64 KB
    int*    sclsv   = (int*)(ws + off);    off += (size_t)BN * 4;       //  64 KB
    int*    rank    = (int*)(ws + off);    off += (size_t)BN * 4;       //  64 KB  (~1.4 MB)

    void* args[] = {&boxes, &box_scores, &cls_preds, &out,
                    &boxes_c, &conf, &clsval, &key64, &rank,
                    &sobox, &sdet, &sclsv};
    hipLaunchCooperativeKernel((const void*)mega, dim3(256), dim3(256),
                               args, 0, stream);
}

// Round 5
// 108.468 us; speedup vs baseline: 1.8745x; 1.8745x over previous
//
#include <hip/hip_runtime.h>
#include <stdint.h>

// Bitwise reproducibility vs the numpy reference: forbid a*b+c fusion so every
// mul/add rounds exactly like the ref (keep-decision booleans must not flip).
#pragma clang fp contract(off)

typedef unsigned long long u64;
typedef unsigned int u32;
typedef unsigned short u16;

namespace {
constexpr int BB = 4;
constexpr int NN = 4096;
constexpr int CC = 64;
constexpr int BN = BB * NN;
constexpr float TARGET = 560.0f;
constexpr float MIN_BOX = 5.0f;
constexpr float IOU_THR = 0.2f;
constexpr float CONF_THR = 0.001f;
constexpr float BOX_CONF_THR = 0.01f;
constexpr float MAX_WH = 4096.0f;
constexpr int MAXK = 2048;   // per-(batch,class) hard cap; data has ~64 +/- 8 per class
}

__device__ __forceinline__ void zero_row(float* __restrict__ out, int p) {
    float2* o2 = (float2*)(out + (size_t)p * 6);   // p*24B is 8B-aligned
    float2 z; z.x = 0.0f; z.y = 0.0f;
    o2[0] = z; o2[1] = z; o2[2] = z;
}

__device__ __forceinline__ void emit_row(float* __restrict__ out, int p,
                                         float4 bc, float cf, float cls) {
    float2* o2 = (float2*)(out + (size_t)p * 6);
    float2 aa; aa.x = bc.x; aa.y = bc.y;
    float2 cc; cc.x = bc.z; cc.y = bc.w;
    float2 ee; ee.x = cf;   ee.y = cls;
    o2[0] = aa; o2[1] = cc; o2[2] = ee;
}

// IoU(i,j) > thr with the ref's exact op order (offset boxes, precomputed areas,
// inter/(ai+aj-inter+1e-9) with IEEE division).
__device__ __forceinline__ bool iou_gt(float4 bi, float ai, float4 bj, float aj) {
    float ltx = fmaxf(bi.x, bj.x);
    float lty = fmaxf(bi.y, bj.y);
    float rbx = fminf(bi.z, bj.z);
    float rby = fminf(bi.w, bj.w);
    float ww = fmaxf(rbx - ltx, 0.0f);
    float hh = fmaxf(rby - lty, 0.0f);
    float inter = ww * hh;
    float iou = inter / (ai + aj - inter + 1e-9f);
    return iou > IOU_THR;
}

// ---------------- k1: clip, conf=max_c(cls*score), argmax, valid, unique 44-bit
// key (score-map<<12 | reversed idx), zero the rank buffer. 4 lanes per row.
__global__ __launch_bounds__(256) void k1_score(const float* __restrict__ boxes,
                                                const float* __restrict__ box_scores,
                                                const float* __restrict__ cls_preds,
                                                float4* __restrict__ boxes_c,
                                                float* __restrict__ conf,
                                                int* __restrict__ clsval,
                                                u64* __restrict__ key64,
                                                int* __restrict__ rank) {
    int r = (blockIdx.x << 6) + (threadIdx.x >> 2);   // 64 rows/block
    int sub = threadIdx.x & 3;
    float bs = box_scores[r];
    const float4* cp = (const float4*)(cls_preds + ((size_t)r << 6) + (sub << 4));
    float best = -1.0f;   // products >= 0, so first element always beats init
    int bestc = sub << 4;
#pragma unroll
    for (int q = 0; q < 4; ++q) {
        float4 v = cp[q];
        float p0 = v.x * bs, p1 = v.y * bs, p2 = v.z * bs, p3 = v.w * bs;
        int cb = (sub << 4) + (q << 2);
        // strict > preserves numpy first-occurrence argmax within a lane
        if (p0 > best) { best = p0; bestc = cb + 0; }
        if (p1 > best) { best = p1; bestc = cb + 1; }
        if (p2 > best) { best = p2; bestc = cb + 2; }
        if (p3 > best) { best = p3; bestc = cb + 3; }
    }
    // quad merge; exact-tie -> smaller class index == first occurrence
#pragma unroll
    for (int d2 = 1; d2 < 4; d2 <<= 1) {
        float ob = __shfl_xor(best, d2);
        int oc = __shfl_xor(bestc, d2);
        if (ob > best || (ob == best && oc < bestc)) { best = ob; bestc = oc; }
    }
    if (sub == 0) {
        float4 bx = ((const float4*)boxes)[r];
        float x1 = fminf(fmaxf(bx.x, 0.0f), TARGET);
        float y1 = fminf(fmaxf(bx.y, 0.0f), TARGET);
        float x2 = fminf(fmaxf(bx.z, 0.0f), TARGET);
        float y2 = fminf(fmaxf(bx.w, 0.0f), TARGET);
        float w = x2 - x1, h = y2 - y1;
        bool valid = (bs > BOX_CONF_THR) && (w > MIN_BOX) && (h > MIN_BOX) && (best > CONF_THR);
        float sk = valid ? best : -1.0f;
        // monotonic float->uint map; unique key: ties (all invalid at -1.0) rank
        // smaller original index first => stable descending sort by score.
        unsigned fb = __float_as_uint(sk);
        unsigned mm = (fb & 0x80000000u) ? ~fb : (fb | 0x80000000u);
        int i = r & (NN - 1);
        key64[r] = ((u64)mm << 12) | (u64)(NN - 1 - i);
        float4 bc; bc.x = x1; bc.y = y1; bc.z = x2; bc.w = y2;
        boxes_c[r] = bc;
        conf[r] = best;
        clsval[r] = bestc | (valid ? 0x10000 : 0);
        rank[r] = 0;   // k2_rank accumulates with atomics
    }
}

// ---------------- k2: rank_i = #{j in batch: key_j > key_i}. Scan split 4 ways
// per element across blocks; exact int atomic accumulation. 256 blocks full-chip.
__global__ __launch_bounds__(256) void k2_rank(const u64* __restrict__ key64,
                                               int* __restrict__ rank) {
    __shared__ u64 sk[1024];   // 8 KB: this block's key chunk
    int bid = blockIdx.x;
    int kseg = bid & 3;          // which 1024-key chunk we scan
    int eseg = (bid >> 2) & 15;  // which 256 elements we own
    int b    = bid >> 6;
    int tid = threadIdx.x;
    const u64* kb = key64 + ((size_t)b << 12);
    for (int p = tid; p < 1024; p += 256) sk[p] = kb[(kseg << 10) + p];
    __syncthreads();
    int i = (eseg << 8) + tid;
    u64 my = kb[i];
    int r = 0;
    const ulonglong2* s2 = (const ulonglong2*)sk;   // b128 reads, 2 keys each
#pragma unroll 8
    for (int q = 0; q < 512; ++q) {
        ulonglong2 v = s2[q];
        r += (int)(v.x > my) + (int)(v.y > my);
    }
    atomicAdd(&rank[(b << 12) + i], r);
}

// ---------------- k3: one wave per (batch,class). Cross-class IoU is exactly 0
// (offset >= 4096 > extent), so global greedy NMS == independent per-class greedy
// in global-rank order. Output row of element e IS rank[e], so no scatter pass:
// build a 4096-bit rank-bitset + rank->element map in LDS, compact, bit-matrix NMS.
// This block owns every row whose element's argmax class == myc: invalid -> zero,
// suppressed -> zero, kept -> det row. Full coverage of d_out (poisoned each call).
__global__ __launch_bounds__(64) void k3_nms(const float4* __restrict__ boxes_c,
                                             const float* __restrict__ conf,
                                             const int* __restrict__ clsval,
                                             const int* __restrict__ rank,
                                             float* __restrict__ out) {
    __shared__ u32 bitset[128];     // 4096 bits over sorted positions (ranks)
    __shared__ u16 pos2e[NN];       // 8 KB: rank -> element index (owned ranks only)
    __shared__ int lpos[MAXK];      // 8 KB: compact index -> rank
    __shared__ float4 lbox[MAXK];   // 32 KB (fast path uses [0..127])
    __shared__ float larea[128];
    const int lane = threadIdx.x;
    const int b = blockIdx.x >> 6;
    const int myc = blockIdx.x & 63;
    const int base = b << 12;       // element base == output row base
    const float off = (float)myc * MAX_WH;   // exact (c * 2^12)

    bitset[2 * lane] = 0;
    bitset[2 * lane + 1] = 0;
    __syncthreads();

    // --- Phase A: mark owned ranks; invalid-but-owned -> zero rows now ---
    const int4* cvp = (const int4*)(clsval + base);
    const int4* rkp = (const int4*)(rank + base);
#pragma unroll
    for (int q = 0; q < 16; ++q) {
        int4 cv = cvp[(q << 6) + lane];   // coalesced, L2-hot (64 blocks share)
        int4 rk = rkp[(q << 6) + lane];
        int e = (q << 8) + (lane << 2);
        if ((cv.x & 0xFF) == myc) {
            if (cv.x & 0x10000) { atomicOr(&bitset[rk.x >> 5], 1u << (rk.x & 31)); pos2e[rk.x] = (u16)(e + 0); }
            else zero_row(out, base + rk.x);
        }
        if ((cv.y & 0xFF) == myc) {
            if (cv.y & 0x10000) { atomicOr(&bitset[rk.y >> 5], 1u << (rk.y & 31)); pos2e[rk.y] = (u16)(e + 1); }
            else zero_row(out, base + rk.y);
        }
        if ((cv.z & 0xFF) == myc) {
            if (cv.z & 0x10000) { atomicOr(&bitset[rk.z >> 5], 1u << (rk.z & 31)); pos2e[rk.z] = (u16)(e + 2); }
            else zero_row(out, base + rk.z);
        }
        if ((cv.w & 0xFF) == myc) {
            if (cv.w & 0x10000) { atomicOr(&bitset[rk.w >> 5], 1u << (rk.w & 31)); pos2e[rk.w] = (u16)(e + 3); }
            else zero_row(out, base + rk.w);
        }
    }
    __syncthreads();

    // --- Phase B: compact ranks ascending (lane owns ranks [64*lane, 64*lane+64)) ---
    u64 w = ((u64)bitset[2 * lane + 1] << 32) | (u64)bitset[2 * lane];
    int cnt = (int)__popcll(w);
    int incl = cnt;
#pragma unroll
    for (int d2 = 1; d2 < 64; d2 <<= 1) {
        int t2 = __shfl_up(incl, d2);
        if (lane >= d2) incl += t2;
    }
    int kk = __shfl(incl, 63);
    {
        int d = incl - cnt;
        u64 t = w;
        while (t) {
            int b2 = (int)__builtin_ctzll(t); t &= t - 1;
            int p = (lane << 6) + b2;
            if (d < MAXK) lpos[d] = p; else zero_row(out, base + p);
            d++;
        }
    }
    if (kk > MAXK) kk = MAXK;
    if (kk == 0) return;
    __syncthreads();

    if (kk <= 128) {
        // --- fast path: k x k IoU bit-matrix in registers, register-only greedy ---
        const int j0 = lane, j1 = 64 + lane;
        bool in0 = j0 < kk, in1 = j1 < kk;
        float4 box0 = {0, 0, 0, 0}, box1 = {0, 0, 0, 0};
        float a0 = 0.0f, a1 = 0.0f;
        if (in0) {
            float4 bc = boxes_c[base + pos2e[lpos[j0]]];
            box0.x = bc.x + off; box0.y = bc.y + off; box0.z = bc.z + off; box0.w = bc.w + off;
            a0 = (box0.z - box0.x) * (box0.w - box0.y);   // ref: area on offset boxes
            lbox[j0] = box0; larea[j0] = a0;
        }
        if (in1) {
            float4 bc = boxes_c[base + pos2e[lpos[j1]]];
            box1.x = bc.x + off; box1.y = bc.y + off; box1.z = bc.z + off; box1.w = bc.w + off;
            a1 = (box1.z - box1.x) * (box1.w - box1.y);
            lbox[j1] = box1; larea[j1] = a1;
        }
        __syncthreads();
        u64 r00 = 0, r10 = 0, r11 = 0;   // bit i of column j: iou(i,j) > thr
        if (kk <= 64) {
            for (int i = 0; i < kk; ++i) {   // independent iterations -> pipelined
                float4 bi = lbox[i];
                float ai = larea[i];
                bool s0 = in0 && (j0 > i) && iou_gt(bi, ai, box0, a0);
                r00 |= ((u64)s0) << i;
            }
        } else {
            for (int i = 0; i < kk; ++i) {
                float4 bi = lbox[i];
                float ai = larea[i];
                bool s0 = in0 && (j0 > i) && iou_gt(bi, ai, box0, a0);
                bool s1 = in1 && (j1 > i) && iou_gt(bi, ai, box1, a1);
                if (i < 64) { r00 |= ((u64)s0) << i; r10 |= ((u64)s1) << i; }
                else        { r11 |= ((u64)s1) << (i - 64); }
            }
        }
        // greedy scan, ~15 register cycles per step (validated r4, absmax 0)
        u32 sup0 = 0, sup1 = 0;
        int kc = kk < 64 ? kk : 64;
        for (int i = 0; i < kc; ++i) {
            u64 f = __ballot(sup0 != 0);
            u32 km = ((f >> i) & 1ull) ? 0u : ~0u;   // keep_i mask
            sup0 |= km & (u32)((r00 >> i) & 1ull);
            sup1 |= km & (u32)((r10 >> i) & 1ull);
        }
        for (int i = 64; i < kk; ++i) {
            u64 f = __ballot(sup1 != 0);
            u32 km = ((f >> (i - 64)) & 1ull) ? 0u : ~0u;
            sup1 |= km & (u32)((r11 >> (i - 64)) & 1ull);
        }
        // emit
        if (in0) {
            int p = lpos[j0]; int e = base + pos2e[p];
            if (!sup0) emit_row(out, base + p, boxes_c[e], conf[e], (float)myc);
            else zero_row(out, base + p);
        }
        if (in1) {
            int p = lpos[j1]; int e = base + pos2e[p];
            if (!sup1) emit_row(out, base + p, boxes_c[e], conf[e], (float)myc);
            else zero_row(out, base + p);
        }
    } else {
        // --- general fallback (never taken on bench data; correctness net) ---
        for (int m = lane; m < kk; m += 64) {
            float4 bc = boxes_c[base + pos2e[lpos[m]]];
            float4 ob; ob.x = bc.x + off; ob.y = bc.y + off; ob.z = bc.z + off; ob.w = bc.w + off;
            lbox[m] = ob;
        }
        __syncthreads();
        u64 supw = 0;   // lane w owns suppression bits [64w, 64w+64)
        for (int i = 0; i < kk; ++i) {
            u64 wd = __shfl(supw, i >> 6);
            if (((wd >> (i & 63)) & 1ull) == 0ull) {
                float4 bi = lbox[i];
                float ai = (bi.z - bi.x) * (bi.w - bi.y);
                for (int jb = (i + 1) & ~63; jb < kk; jb += 64) {
                    int j = jb + lane;
                    bool s = false;
                    if (j > i && j < kk) {
                        float4 bj = lbox[j];
                        float aj = (bj.z - bj.x) * (bj.w - bj.y);
                        s = iou_gt(bi, ai, bj, aj);
                    }
                    u64 m2 = __ballot(s);
                    if (lane == (jb >> 6)) supw |= m2;
                }
            }
        }
        for (int t2 = 0; t2 * 64 < kk; ++t2) {
            int m = t2 * 64 + lane;
            u64 wd = __shfl(supw, t2);
            if (m < kk) {
                int p = lpos[m]; int e = base + pos2e[p];
                if (((wd >> lane) & 1ull) == 0ull)
                    emit_row(out, base + p, boxes_c[e], conf[e], (float)myc);
                else zero_row(out, base + p);
            }
        }
    }
}

extern "C" void kernel_launch(void* const* d_in, const int* in_sizes, int n_in,
                              void* d_out, int out_size, void* d_ws, size_t ws_size,
                              hipStream_t stream) {
    const float* boxes      = (const float*)d_in[0];   // [B,N,4]
    const float* box_scores = (const float*)d_in[1];   // [B,N]
    const float* cls_preds  = (const float*)d_in[2];   // [B,N,C]

    char* ws = (char*)d_ws;
    size_t off = 0;
    float4* boxes_c = (float4*)(ws + off); off += (size_t)BN * 16;      // 256 KB
    u64*    key64   = (u64*)(ws + off);    off += (size_t)BN * 8;       // 128 KB
    float*  conf    = (float*)(ws + off);  off += (size_t)BN * 4;       //  64 KB
    int*    clsval  = (int*)(ws + off);    off += (size_t)BN * 4;       //  64 KB
    int*    rank    = (int*)(ws + off);    off += (size_t)BN * 4;       //  64 KB (~576 KB)

    k1_score<<<BN / 64, 256, 0, stream>>>(boxes, box_scores, cls_preds,
                                          boxes_c, conf, clsval, key64, rank);
    k2_rank<<<BB * 64, 256, 0, stream>>>(key64, rank);
    k3_nms<<<BB * CC, 64, 0, stream>>>(boxes_c, conf, clsval, rank, (float*)d_out);
}

// Round 6
// 103.040 us; speedup vs baseline: 1.9733x; 1.0527x over previous
//
#include <hip/hip_runtime.h>
#include <stdint.h>

// Bitwise reproducibility vs the numpy reference: forbid a*b+c fusion so every
// mul/add rounds exactly like the ref (keep-decision booleans must not flip).
#pragma clang fp contract(off)

typedef unsigned long long u64;
typedef unsigned int u32;
typedef unsigned short u16;

namespace {
constexpr int BB = 4;
constexpr int NN = 4096;
constexpr int CC = 64;
constexpr int BN = BB * NN;
constexpr float TARGET = 560.0f;
constexpr float MIN_BOX = 5.0f;
constexpr float IOU_THR = 0.2f;
constexpr float CONF_THR = 0.001f;
constexpr float BOX_CONF_THR = 0.01f;
constexpr float MAX_WH = 4096.0f;
constexpr int MAXK = 2048;   // per-(batch,class) hard cap; data has ~64 +/- 8 per class
}

__device__ __forceinline__ void zero_row(float* __restrict__ out, int p) {
    float2* o2 = (float2*)(out + (size_t)p * 6);   // p*24B is 8B-aligned
    float2 z; z.x = 0.0f; z.y = 0.0f;
    o2[0] = z; o2[1] = z; o2[2] = z;
}

__device__ __forceinline__ void emit_row(float* __restrict__ out, int p,
                                         float4 bc, float cf, float cls) {
    float2* o2 = (float2*)(out + (size_t)p * 6);
    float2 aa; aa.x = bc.x; aa.y = bc.y;
    float2 cc; cc.x = bc.z; cc.y = bc.w;
    float2 ee; ee.x = cf;   ee.y = cls;
    o2[0] = aa; o2[1] = cc; o2[2] = ee;
}

// IoU(i,j) > thr with the ref's exact op order (offset boxes, precomputed areas,
// inter/(ai+aj-inter+1e-9) with IEEE division).
__device__ __forceinline__ bool iou_gt(float4 bi, float ai, float4 bj, float aj) {
    float ltx = fmaxf(bi.x, bj.x);
    float lty = fmaxf(bi.y, bj.y);
    float rbx = fminf(bi.z, bj.z);
    float rby = fminf(bi.w, bj.w);
    float ww = fmaxf(rbx - ltx, 0.0f);
    float hh = fmaxf(rby - lty, 0.0f);
    float inter = ww * hh;
    float iou = inter / (ai + aj - inter + 1e-9f);
    return iou > IOU_THR;
}

// ---------------- k1: clip, conf=max_c(cls*score), argmax, valid, unique 44-bit
// key (score-map<<12 | reversed idx), zero the rank buffer. 4 lanes per row.
__global__ __launch_bounds__(256) void k1_score(const float* __restrict__ boxes,
                                                const float* __restrict__ box_scores,
                                                const float* __restrict__ cls_preds,
                                                float4* __restrict__ boxes_c,
                                                float* __restrict__ conf,
                                                int* __restrict__ clsval,
                                                u64* __restrict__ key64,
                                                int* __restrict__ rank) {
    int r = (blockIdx.x << 6) + (threadIdx.x >> 2);   // 64 rows/block
    int sub = threadIdx.x & 3;
    float bs = box_scores[r];
    const float4* cp = (const float4*)(cls_preds + ((size_t)r << 6) + (sub << 4));
    float best = -1.0f;   // products >= 0, so first element always beats init
    int bestc = sub << 4;
#pragma unroll
    for (int q = 0; q < 4; ++q) {
        float4 v = cp[q];
        float p0 = v.x * bs, p1 = v.y * bs, p2 = v.z * bs, p3 = v.w * bs;
        int cb = (sub << 4) + (q << 2);
        // strict > preserves numpy first-occurrence argmax within a lane
        if (p0 > best) { best = p0; bestc = cb + 0; }
        if (p1 > best) { best = p1; bestc = cb + 1; }
        if (p2 > best) { best = p2; bestc = cb + 2; }
        if (p3 > best) { best = p3; bestc = cb + 3; }
    }
    // quad merge; exact-tie -> smaller class index == first occurrence
#pragma unroll
    for (int d2 = 1; d2 < 4; d2 <<= 1) {
        float ob = __shfl_xor(best, d2);
        int oc = __shfl_xor(bestc, d2);
        if (ob > best || (ob == best && oc < bestc)) { best = ob; bestc = oc; }
    }
    if (sub == 0) {
        float4 bx = ((const float4*)boxes)[r];
        float x1 = fminf(fmaxf(bx.x, 0.0f), TARGET);
        float y1 = fminf(fmaxf(bx.y, 0.0f), TARGET);
        float x2 = fminf(fmaxf(bx.z, 0.0f), TARGET);
        float y2 = fminf(fmaxf(bx.w, 0.0f), TARGET);
        float w = x2 - x1, h = y2 - y1;
        bool valid = (bs > BOX_CONF_THR) && (w > MIN_BOX) && (h > MIN_BOX) && (best > CONF_THR);
        float sk = valid ? best : -1.0f;
        // monotonic float->uint map; unique key: ties (all invalid at -1.0) rank
        // smaller original index first => stable descending sort by score.
        unsigned fb = __float_as_uint(sk);
        unsigned mm = (fb & 0x80000000u) ? ~fb : (fb | 0x80000000u);
        int i = r & (NN - 1);
        key64[r] = ((u64)mm << 12) | (u64)(NN - 1 - i);
        float4 bc; bc.x = x1; bc.y = y1; bc.z = x2; bc.w = y2;
        boxes_c[r] = bc;
        conf[r] = best;
        clsval[r] = bestc | (valid ? 0x10000 : 0);
        rank[r] = 0;   // k2_rank accumulates with atomics
    }
}

// ---------------- k2: rank_i = #{j in batch: key_j > key_i}. Scan split 8 ways
// per element across blocks (512 blocks = 2048 waves, ~512 cmp/lane); exact int
// atomic accumulation (8 partials per element).
__global__ __launch_bounds__(256) void k2_rank(const u64* __restrict__ key64,
                                               int* __restrict__ rank) {
    __shared__ u64 sk[512];      // 4 KB: this block's 512-key chunk
    int bid = blockIdx.x;
    int kseg = bid & 7;          // which 512-key chunk we scan
    int eseg = (bid >> 3) & 15;  // which 256 elements we own
    int b    = bid >> 7;
    int tid = threadIdx.x;
    const u64* kb = key64 + ((size_t)b << 12);
    for (int p = tid; p < 512; p += 256) sk[p] = kb[(kseg << 9) + p];
    __syncthreads();
    int i = (eseg << 8) + tid;
    u64 my = kb[i];
    int r = 0;
    const ulonglong2* s2 = (const ulonglong2*)sk;   // b128 reads, 2 keys each
#pragma unroll 16
    for (int q = 0; q < 256; ++q) {
        ulonglong2 v = s2[q];
        r += (int)(v.x > my) + (int)(v.y > my);
    }
    atomicAdd(&rank[(b << 12) + i], r);
}

// ---------------- k3: one wave per (batch,class). Cross-class IoU is exactly 0
// (offset >= 4096 > extent), so global greedy NMS == independent per-class greedy
// in global-rank order. Output row of element e IS rank[e], so no scatter pass:
// build a 4096-bit rank-bitset + rank->element map in LDS, compact, bit-matrix NMS.
// This block owns every row whose element's argmax class == myc: invalid -> zero,
// suppressed -> zero, kept -> det row. Full coverage of d_out (poisoned each call).
__global__ __launch_bounds__(64) void k3_nms(const float4* __restrict__ boxes_c,
                                             const float* __restrict__ conf,
                                             const int* __restrict__ clsval,
                                             const int* __restrict__ rank,
                                             float* __restrict__ out) {
    __shared__ u32 bitset[128];     // 4096 bits over sorted positions (ranks)
    __shared__ u16 pos2e[NN];       // 8 KB: rank -> element index (owned ranks only)
    __shared__ int lpos[MAXK];      // 8 KB: compact index -> rank
    __shared__ float4 lbox[MAXK];   // 32 KB (fast path uses [0..127])
    __shared__ float larea[128];
    const int lane = threadIdx.x;
    const int b = blockIdx.x >> 6;
    const int myc = blockIdx.x & 63;
    const int base = b << 12;       // element base == output row base
    const float off = (float)myc * MAX_WH;   // exact (c * 2^12)

    bitset[2 * lane] = 0;
    bitset[2 * lane + 1] = 0;
    __syncthreads();

    // --- Phase A: mark owned ranks; invalid-but-owned -> zero rows now ---
    const int4* cvp = (const int4*)(clsval + base);
    const int4* rkp = (const int4*)(rank + base);
#pragma unroll
    for (int q = 0; q < 16; ++q) {
        int4 cv = cvp[(q << 6) + lane];   // coalesced, L2-hot (64 blocks share)
        int4 rk = rkp[(q << 6) + lane];
        int e = (q << 8) + (lane << 2);
        if ((cv.x & 0xFF) == myc) {
            if (cv.x & 0x10000) { atomicOr(&bitset[rk.x >> 5], 1u << (rk.x & 31)); pos2e[rk.x] = (u16)(e + 0); }
            else zero_row(out, base + rk.x);
        }
        if ((cv.y & 0xFF) == myc) {
            if (cv.y & 0x10000) { atomicOr(&bitset[rk.y >> 5], 1u << (rk.y & 31)); pos2e[rk.y] = (u16)(e + 1); }
            else zero_row(out, base + rk.y);
        }
        if ((cv.z & 0xFF) == myc) {
            if (cv.z & 0x10000) { atomicOr(&bitset[rk.z >> 5], 1u << (rk.z & 31)); pos2e[rk.z] = (u16)(e + 2); }
            else zero_row(out, base + rk.z);
        }
        if ((cv.w & 0xFF) == myc) {
            if (cv.w & 0x10000) { atomicOr(&bitset[rk.w >> 5], 1u << (rk.w & 31)); pos2e[rk.w] = (u16)(e + 3); }
            else zero_row(out, base + rk.w);
        }
    }
    __syncthreads();

    // --- Phase B: compact ranks ascending (lane owns ranks [64*lane, 64*lane+64)) ---
    u64 w = ((u64)bitset[2 * lane + 1] << 32) | (u64)bitset[2 * lane];
    int cnt = (int)__popcll(w);
    int incl = cnt;
#pragma unroll
    for (int d2 = 1; d2 < 64; d2 <<= 1) {
        int t2 = __shfl_up(incl, d2);
        if (lane >= d2) incl += t2;
    }
    int kk = __shfl(incl, 63);
    {
        int d = incl - cnt;
        u64 t = w;
        while (t) {
            int b2 = (int)__builtin_ctzll(t); t &= t - 1;
            int p = (lane << 6) + b2;
            if (d < MAXK) lpos[d] = p; else zero_row(out, base + p);
            d++;
        }
    }
    if (kk > MAXK) kk = MAXK;
    if (kk == 0) return;
    __syncthreads();

    if (kk <= 128) {
        // --- fast path: k x k IoU bit-matrix in registers, register-only greedy ---
        const int j0 = lane, j1 = 64 + lane;
        bool in0 = j0 < kk, in1 = j1 < kk;
        float4 box0 = {0, 0, 0, 0}, box1 = {0, 0, 0, 0};
        float a0 = 0.0f, a1 = 0.0f;
        if (in0) {
            float4 bc = boxes_c[base + pos2e[lpos[j0]]];
            box0.x = bc.x + off; box0.y = bc.y + off; box0.z = bc.z + off; box0.w = bc.w + off;
            a0 = (box0.z - box0.x) * (box0.w - box0.y);   // ref: area on offset boxes
            lbox[j0] = box0; larea[j0] = a0;
        }
        if (in1) {
            float4 bc = boxes_c[base + pos2e[lpos[j1]]];
            box1.x = bc.x + off; box1.y = bc.y + off; box1.z = bc.z + off; box1.w = bc.w + off;
            a1 = (box1.z - box1.x) * (box1.w - box1.y);
            lbox[j1] = box1; larea[j1] = a1;
        }
        __syncthreads();
        u64 r00 = 0, r10 = 0, r11 = 0;   // bit i of column j: iou(i,j) > thr
        if (kk <= 64) {
            for (int i = 0; i < kk; ++i) {   // independent iterations -> pipelined
                float4 bi = lbox[i];
                float ai = larea[i];
                bool s0 = in0 && (j0 > i) && iou_gt(bi, ai, box0, a0);
                r00 |= ((u64)s0) << i;
            }
        } else {
            for (int i = 0; i < kk; ++i) {
                float4 bi = lbox[i];
                float ai = larea[i];
                bool s0 = in0 && (j0 > i) && iou_gt(bi, ai, box0, a0);
                bool s1 = in1 && (j1 > i) && iou_gt(bi, ai, box1, a1);
                if (i < 64) { r00 |= ((u64)s0) << i; r10 |= ((u64)s1) << i; }
                else        { r11 |= ((u64)s1) << (i - 64); }
            }
        }
        // greedy scan, ~15 register cycles per step (validated r4/r5, absmax 0)
        u32 sup0 = 0, sup1 = 0;
        int kc = kk < 64 ? kk : 64;
        for (int i = 0; i < kc; ++i) {
            u64 f = __ballot(sup0 != 0);
            u32 km = ((f >> i) & 1ull) ? 0u : ~0u;   // keep_i mask
            sup0 |= km & (u32)((r00 >> i) & 1ull);
            sup1 |= km & (u32)((r10 >> i) & 1ull);
        }
        for (int i = 64; i < kk; ++i) {
            u64 f = __ballot(sup1 != 0);
            u32 km = ((f >> (i - 64)) & 1ull) ? 0u : ~0u;
            sup1 |= km & (u32)((r11 >> (i - 64)) & 1ull);
        }
        // emit
        if (in0) {
            int p = lpos[j0]; int e = base + pos2e[p];
            if (!sup0) emit_row(out, base + p, boxes_c[e], conf[e], (float)myc);
            else zero_row(out, base + p);
        }
        if (in1) {
            int p = lpos[j1]; int e = base + pos2e[p];
            if (!sup1) emit_row(out, base + p, boxes_c[e], conf[e], (float)myc);
            else zero_row(out, base + p);
        }
    } else {
        // --- general fallback (never taken on bench data; correctness net) ---
        for (int m = lane; m < kk; m += 64) {
            float4 bc = boxes_c[base + pos2e[lpos[m]]];
            float4 ob; ob.x = bc.x + off; ob.y = bc.y + off; ob.z = bc.z + off; ob.w = bc.w + off;
            lbox[m] = ob;
        }
        __syncthreads();
        u64 supw = 0;   // lane w owns suppression bits [64w, 64w+64)
        for (int i = 0; i < kk; ++i) {
            u64 wd = __shfl(supw, i >> 6);
            if (((wd >> (i & 63)) & 1ull) == 0ull) {
                float4 bi = lbox[i];
                float ai = (bi.z - bi.x) * (bi.w - bi.y);
                for (int jb = (i + 1) & ~63; jb < kk; jb += 64) {
                    int j = jb + lane;
                    bool s = false;
                    if (j > i && j < kk) {
                        float4 bj = lbox[j];
                        float aj = (bj.z - bj.x) * (bj.w - bj.y);
                        s = iou_gt(bi, ai, bj, aj);
                    }
                    u64 m2 = __ballot(s);
                    if (lane == (jb >> 6)) supw |= m2;
                }
            }
        }
        for (int t2 = 0; t2 * 64 < kk; ++t2) {
            int m = t2 * 64 + lane;
            u64 wd = __shfl(supw, t2);
            if (m < kk) {
                int p = lpos[m]; int e = base + pos2e[p];
                if (((wd >> lane) & 1ull) == 0ull)
                    emit_row(out, base + p, boxes_c[e], conf[e], (float)myc);
                else zero_row(out, base + p);
            }
        }
    }
}

extern "C" void kernel_launch(void* const* d_in, const int* in_sizes, int n_in,
                              void* d_out, int out_size, void* d_ws, size_t ws_size,
                              hipStream_t stream) {
    const float* boxes      = (const float*)d_in[0];   // [B,N,4]
    const float* box_scores = (const float*)d_in[1];   // [B,N]
    const float* cls_preds  = (const float*)d_in[2];   // [B,N,C]

    char* ws = (char*)d_ws;
    size_t off = 0;
    float4* boxes_c = (float4*)(ws + off); off += (size_t)BN * 16;      // 256 KB
    u64*    key64   = (u64*)(ws + off);    off += (size_t)BN * 8;       // 128 KB
    float*  conf    = (float*)(ws + off);  off += (size_t)BN * 4;       //  64 KB
    int*    clsval  = (int*)(ws + off);    off += (size_t)BN * 4;       //  64 KB
    int*    rank    = (int*)(ws + off);    off += (size_t)BN * 4;       //  64 KB (~576 KB)

    k1_score<<<BN / 64, 256, 0, stream>>>(boxes, box_scores, cls_preds,
                                          boxes_c, conf, clsval, key64, rank);
    k2_rank<<<BB * 128, 256, 0, stream>>>(key64, rank);
    k3_nms<<<BB * CC, 64, 0, stream>>>(boxes_c, conf, clsval, rank, (float*)d_out);
}